// Round 2
// baseline (207.537 us; speedup 1.0000x reference)
//
#include <hip/hip_runtime.h>
#include <hip/hip_bf16.h>

#define S 4096
#define D 1024
#define NH 16
#define HD 64

typedef float f32x4 __attribute__((ext_vector_type(4)));
typedef __bf16 bf16x8 __attribute__((ext_vector_type(8)));

#define MFMA16(a, b, c) __builtin_amdgcn_mfma_f32_16x16x32_bf16((a), (b), (c), 0, 0, 0)

__device__ __forceinline__ unsigned short f2bf(float f) {
  unsigned int u = __builtin_bit_cast(unsigned int, f);
  u += 0x7FFFu + ((u >> 16) & 1u);
  return (unsigned short)(u >> 16);
}

typedef __attribute__((address_space(1))) void GAS;
typedef __attribute__((address_space(3))) void LAS;

__device__ __forceinline__ void gld_lds16(const unsigned short* g, unsigned short* l) {
  __builtin_amdgcn_global_load_lds((GAS*)g, (LAS*)l, 16, 0, 0);
}

// ---------------------------------------------------------------------------
// f32 -> bf16 convert (vectorized float4 -> ushort4)
// ---------------------------------------------------------------------------
__global__ void cvt_bf16(const float* __restrict__ in, unsigned short* __restrict__ out, int n4) {
  int i = blockIdx.x * blockDim.x + threadIdx.x;
  if (i >= n4) return;
  float4 v = ((const float4*)in)[i];
  ushort4 u;
  u.x = f2bf(v.x); u.y = f2bf(v.y); u.z = f2bf(v.z); u.w = f2bf(v.w);
  ((ushort4*)out)[i] = u;
}

// ---------------------------------------------------------------------------
// C[M x N] f32 = A[M x K]bf16 @ B[N x K]^T bf16 + bias[N]
// 128x128 tile, BK=32, 256 threads (4 waves 2x2), mfma 16x16x32.
// ---------------------------------------------------------------------------
__global__ __launch_bounds__(256) void gemm_bt(const unsigned short* __restrict__ A,
                                               const unsigned short* __restrict__ B,
                                               const float* __restrict__ bias,
                                               float* __restrict__ C,
                                               int M, int N, int K) {
  __shared__ __align__(16) unsigned short As[128 * 32];
  __shared__ __align__(16) unsigned short Bs[128 * 32];
  const int t = threadIdx.x;
  const int lane = t & 63;
  const int w = t >> 6;
  const int wr = w >> 1, wc = w & 1;
  const int l15 = lane & 15, l4 = lane >> 4;
  const int m0 = blockIdx.y * 128, n0 = blockIdx.x * 128;

  f32x4 acc[4][4] = {};

  const int c0 = t, c1 = 256 + t;
  const int r0 = c0 >> 2, o0 = (c0 & 3) * 8;
  const int r1 = c1 >> 2, o1 = (c1 & 3) * 8;
  const unsigned short* Ab = A + (size_t)m0 * K;
  const unsigned short* Bb = B + (size_t)n0 * K;

  for (int k0 = 0; k0 < K; k0 += 32) {
    gld_lds16(Ab + (size_t)r0 * K + k0 + o0, &As[(w * 64) * 8]);
    gld_lds16(Ab + (size_t)r1 * K + k0 + o1, &As[(256 + w * 64) * 8]);
    gld_lds16(Bb + (size_t)r0 * K + k0 + o0, &Bs[(w * 64) * 8]);
    gld_lds16(Bb + (size_t)r1 * K + k0 + o1, &Bs[(256 + w * 64) * 8]);
    __syncthreads();
    bf16x8 af[4], bfv[4];
#pragma unroll
    for (int mf = 0; mf < 4; ++mf)
      af[mf] = *(const bf16x8*)&As[(wr * 64 + mf * 16 + l15) * 32 + l4 * 8];
#pragma unroll
    for (int nf = 0; nf < 4; ++nf)
      bfv[nf] = *(const bf16x8*)&Bs[(wc * 64 + nf * 16 + l15) * 32 + l4 * 8];
#pragma unroll
    for (int mf = 0; mf < 4; ++mf)
#pragma unroll
      for (int nf = 0; nf < 4; ++nf)
        acc[mf][nf] = MFMA16(af[mf], bfv[nf], acc[mf][nf]);
    __syncthreads();
  }

#pragma unroll
  for (int mf = 0; mf < 4; ++mf) {
#pragma unroll
    for (int nf = 0; nf < 4; ++nf) {
      int rr = m0 + wr * 64 + mf * 16 + l4 * 4;
      int cc = n0 + wc * 64 + nf * 16 + l15;
      float bv = bias[cc];
#pragma unroll
      for (int j = 0; j < 4; ++j)
        C[(size_t)(rr + j) * N + cc] = acc[mf][nf][j] + bv;
    }
  }
}

// ---------------------------------------------------------------------------
// Per-row RMSNorm (over full D=1024) + RoPE, for q and k parts of qkv.
// Writes head-major bf16: q/k [NH][S][HD].
// ---------------------------------------------------------------------------
__global__ __launch_bounds__(256) void norm_rope(const float* __restrict__ qkv,
                                                 const float* __restrict__ qw,
                                                 const float* __restrict__ kw,
                                                 const float* __restrict__ fr,
                                                 unsigned short* __restrict__ qo,
                                                 unsigned short* __restrict__ ko) {
  __shared__ float buf[1024];
  __shared__ float red[4];
  const int s = blockIdx.x, t = threadIdx.x;
  const int lane = t & 63, w = t >> 6;
  const int e = t * 4;
  const int hh = e >> 6, dd = e & 63;
  const float* frow = fr + (size_t)s * 32;
  float cs[4], sn[4];
#pragma unroll
  for (int i = 0; i < 4; ++i) {
    float f = frow[(dd + i) & 31];
    cs[i] = cosf(f);
    sn[i] = sinf(f);
  }
  for (int part = 0; part < 2; ++part) {
    const float* row = qkv + (size_t)s * 3072 + part * 1024;
    const float* wvp = part ? kw : qw;
    unsigned short* op = part ? ko : qo;
    float4 v = *(const float4*)(row + e);
    float ssq = v.x * v.x + v.y * v.y + v.z * v.z + v.w * v.w;
#pragma unroll
    for (int off = 1; off < 64; off <<= 1) ssq += __shfl_xor(ssq, off, 64);
    if (part) __syncthreads();  // protect red/buf reuse across parts
    if (lane == 0) red[w] = ssq;
    __syncthreads();
    float inv = rsqrtf((red[0] + red[1] + red[2] + red[3]) * (1.0f / 1024.0f) + 1e-6f);
    float4 wv = *(const float4*)(wvp + e);
    buf[e + 0] = v.x * inv * wv.x;
    buf[e + 1] = v.y * inv * wv.y;
    buf[e + 2] = v.z * inv * wv.z;
    buf[e + 3] = v.w * inv * wv.w;
    __syncthreads();
    unsigned short ov[4];
#pragma unroll
    for (int i = 0; i < 4; ++i) {
      int di = dd + i;
      float x = buf[e + i];
      float rot = (di < 32) ? -buf[e + i + 32] : buf[e + i - 32];
      ov[i] = f2bf(x * cs[i] + rot * sn[i]);
    }
    unsigned short* dst = op + (size_t)hh * S * HD + (size_t)s * HD + dd;
    dst[0] = ov[0]; dst[1] = ov[1]; dst[2] = ov[2]; dst[3] = ov[3];
  }
}

// ---------------------------------------------------------------------------
// V: qkv f32 [S][3072] (cols 2048..3071) -> vt bf16 [NH][HD][S] (transposed)
// ---------------------------------------------------------------------------
__global__ __launch_bounds__(256) void vtrans(const float* __restrict__ qkv,
                                              unsigned short* __restrict__ vt) {
  __shared__ unsigned short tile[64][72];
  const int bx = blockIdx.x;
  const int h = bx >> 6, st = bx & 63;
  const int s0 = st * 64;
  const int t = threadIdx.x;
#pragma unroll
  for (int i = 0; i < 16; ++i) {
    int idx = i * 256 + t;
    int sr = idx >> 6, d = idx & 63;
    tile[sr][d] = f2bf(qkv[(size_t)(s0 + sr) * 3072 + 2048 + h * 64 + d]);
  }
  __syncthreads();
#pragma unroll
  for (int i = 0; i < 16; ++i) {
    int idx = i * 256 + t;
    int d = idx >> 6, sr = idx & 63;
    vt[(size_t)h * HD * S + (size_t)d * S + s0 + sr] = tile[sr][d];
  }
}

// ---------------------------------------------------------------------------
// Flash attention within 1024-length segments.
// grid: 512 = NH(16) x seg(4) x qtile(8 of 128 rows). 4 waves x 32 q-rows.
// q,k: [NH][S][HD] bf16;  vt: [NH][HD][S] bf16;  out: [S][D] bf16.
// ---------------------------------------------------------------------------
__global__ __launch_bounds__(256) void attn_kernel(const unsigned short* __restrict__ q,
                                                   const unsigned short* __restrict__ k,
                                                   const unsigned short* __restrict__ vt,
                                                   unsigned short* __restrict__ aout) {
  __shared__ __align__(16) unsigned short P[4][32 * 128];
  const int bx = blockIdx.x;
  const int qt = bx & 7, seg = (bx >> 3) & 3, h = bx >> 5;
  const int t = threadIdx.x, lane = t & 63, w = t >> 6;
  const int l15 = lane & 15, l4 = lane >> 4;
  const int s0 = seg * 1024 + qt * 128 + w * 32;
  const size_t hb = (size_t)h * S * HD;
  const float scale = 0.125f;

  bf16x8 aq[2][2];
#pragma unroll
  for (int mf = 0; mf < 2; ++mf)
#pragma unroll
    for (int ks = 0; ks < 2; ++ks)
      aq[mf][ks] = *(const bf16x8*)(q + hb + (size_t)(s0 + mf * 16 + l15) * HD + ks * 32 + l4 * 8);

  f32x4 o[2][4] = {};
  float mrun[2][4], lrun[2][4];
#pragma unroll
  for (int mf = 0; mf < 2; ++mf)
#pragma unroll
    for (int j = 0; j < 4; ++j) { mrun[mf][j] = -1e30f; lrun[mf][j] = 0.f; }

  for (int it = 0; it < 8; ++it) {
    const int kv0 = seg * 1024 + it * 128;
    f32x4 sa[2][8] = {};
#pragma unroll
    for (int nf = 0; nf < 8; ++nf) {
      const unsigned short* kp = k + hb + (size_t)(kv0 + nf * 16 + l15) * HD + l4 * 8;
      bf16x8 b0 = *(const bf16x8*)kp;
      bf16x8 b1 = *(const bf16x8*)(kp + 32);
      sa[0][nf] = MFMA16(aq[0][0], b0, sa[0][nf]);
      sa[0][nf] = MFMA16(aq[0][1], b1, sa[0][nf]);
      sa[1][nf] = MFMA16(aq[1][0], b0, sa[1][nf]);
      sa[1][nf] = MFMA16(aq[1][1], b1, sa[1][nf]);
    }
    // ---- online softmax ----
    float mloc[2][4];
#pragma unroll
    for (int mf = 0; mf < 2; ++mf)
#pragma unroll
      for (int j = 0; j < 4; ++j) mloc[mf][j] = -1e30f;
#pragma unroll
    for (int mf = 0; mf < 2; ++mf)
#pragma unroll
      for (int nf = 0; nf < 8; ++nf)
#pragma unroll
        for (int j = 0; j < 4; ++j) {
          sa[mf][nf][j] *= scale;
          mloc[mf][j] = fmaxf(mloc[mf][j], sa[mf][nf][j]);
        }
#pragma unroll
    for (int off = 1; off < 16; off <<= 1)
#pragma unroll
      for (int mf = 0; mf < 2; ++mf)
#pragma unroll
        for (int j = 0; j < 4; ++j)
          mloc[mf][j] = fmaxf(mloc[mf][j], __shfl_xor(mloc[mf][j], off, 64));
    float corr[2][4], rsum[2][4];
#pragma unroll
    for (int mf = 0; mf < 2; ++mf)
#pragma unroll
      for (int j = 0; j < 4; ++j) {
        float mn = fmaxf(mrun[mf][j], mloc[mf][j]);
        corr[mf][j] = __expf(mrun[mf][j] - mn);
        mrun[mf][j] = mn;
        rsum[mf][j] = 0.f;
      }
#pragma unroll
    for (int mf = 0; mf < 2; ++mf)
#pragma unroll
      for (int nf = 0; nf < 8; ++nf)
#pragma unroll
        for (int j = 0; j < 4; ++j) {
          float p = __expf(sa[mf][nf][j] - mrun[mf][j]);
          sa[mf][nf][j] = p;
          rsum[mf][j] += p;
        }
#pragma unroll
    for (int off = 1; off < 16; off <<= 1)
#pragma unroll
      for (int mf = 0; mf < 2; ++mf)
#pragma unroll
        for (int j = 0; j < 4; ++j)
          rsum[mf][j] += __shfl_xor(rsum[mf][j], off, 64);
#pragma unroll
    for (int mf = 0; mf < 2; ++mf)
#pragma unroll
      for (int j = 0; j < 4; ++j)
        lrun[mf][j] = lrun[mf][j] * corr[mf][j] + rsum[mf][j];
#pragma unroll
    for (int mf = 0; mf < 2; ++mf)
#pragma unroll
      for (int nf2 = 0; nf2 < 4; ++nf2)
#pragma unroll
        for (int j = 0; j < 4; ++j)
          o[mf][nf2][j] *= corr[mf][j];
    // ---- P (C-frag layout) -> LDS (XOR-swizzled) -> A-frag layout ----
    __syncthreads();
#pragma unroll
    for (int mf = 0; mf < 2; ++mf)
#pragma unroll
      for (int nf = 0; nf < 8; ++nf)
#pragma unroll
        for (int j = 0; j < 4; ++j) {
          int pr = mf * 16 + l4 * 4 + j;
          int pc = nf * 16 + l15;
          int byte = pr * 256 + ((pc * 2) ^ ((pr & 7) << 4));
          *(unsigned short*)((char*)P[w] + byte) = f2bf(sa[mf][nf][j]);
        }
    __syncthreads();
    // ---- O += P @ V ----
#pragma unroll
    for (int ks = 0; ks < 4; ++ks) {
      int cb = ks * 64 + l4 * 16;
      bf16x8 pa0 = *(const bf16x8*)((const char*)P[w] + l15 * 256 + (cb ^ ((l15 & 7) << 4)));
      bf16x8 pa1 = *(const bf16x8*)((const char*)P[w] + (16 + l15) * 256 + (cb ^ ((l15 & 7) << 4)));
#pragma unroll
      for (int nf2 = 0; nf2 < 4; ++nf2) {
        const unsigned short* vp = vt + (size_t)h * HD * S + (size_t)(nf2 * 16 + l15) * S + kv0 + ks * 32 + l4 * 8;
        bf16x8 vb = *(const bf16x8*)vp;
        o[0][nf2] = MFMA16(pa0, vb, o[0][nf2]);
        o[1][nf2] = MFMA16(pa1, vb, o[1][nf2]);
      }
    }
  }
  // epilogue
#pragma unroll
  for (int mf = 0; mf < 2; ++mf) {
    float inv[4];
#pragma unroll
    for (int j = 0; j < 4; ++j) inv[j] = 1.0f / lrun[mf][j];
#pragma unroll
    for (int nf2 = 0; nf2 < 4; ++nf2)
#pragma unroll
      for (int j = 0; j < 4; ++j) {
        int srow = s0 + mf * 16 + l4 * 4 + j;
        int col = h * 64 + nf2 * 16 + l15;
        aout[(size_t)srow * D + col] = f2bf(o[mf][nf2][j] * inv[j]);
      }
  }
}

// ---------------------------------------------------------------------------
extern "C" void kernel_launch(void* const* d_in, const int* in_sizes, int n_in,
                              void* d_out, int out_size, void* d_ws, size_t ws_size,
                              hipStream_t stream) {
  const float* hidden = (const float*)d_in[0];
  const float* qkvw   = (const float*)d_in[1];
  const float* qkvb   = (const float*)d_in[2];
  const float* projw  = (const float*)d_in[3];
  const float* projb  = (const float*)d_in[4];
  const float* qnw    = (const float*)d_in[5];
  const float* knw    = (const float*)d_in[6];
  const float* freqs  = (const float*)d_in[7];
  float* out = (float*)d_out;
  char* ws = (char*)d_ws;

  unsigned short* hb  = (unsigned short*)(ws + 0);               // 8 MB  hidden bf16 [4096][1024]
  unsigned short* wb  = (unsigned short*)(ws + (8u << 20));      // 6 MB  qkv_w bf16 [3072][1024]
  unsigned short* pb  = (unsigned short*)(ws + (14u << 20));     // 2 MB  proj_w bf16 [1024][1024]
  float*          qkv = (float*)(ws + (16u << 20));              // 48 MB qkv f32 [4096][3072]
  unsigned short* qb  = (unsigned short*)(ws + (64u << 20));     // 8 MB  q bf16 [16][4096][64]
  unsigned short* kb  = (unsigned short*)(ws + (72u << 20));     // 8 MB  k bf16 [16][4096][64]
  unsigned short* vtb = (unsigned short*)(ws + (80u << 20));     // 8 MB  v^T bf16 [16][64][4096]
  unsigned short* ab  = (unsigned short*)(ws + (88u << 20));     // 8 MB  attn bf16 [4096][1024]

  cvt_bf16<<<4096, 256, 0, stream>>>(hidden, hb, 1048576);
  cvt_bf16<<<3072, 256, 0, stream>>>(qkvw, wb, 786432);
  cvt_bf16<<<1024, 256, 0, stream>>>(projw, pb, 262144);
  gemm_bt<<<dim3(24, 32), 256, 0, stream>>>(hb, wb, qkvb, qkv, 4096, 3072, 1024);
  norm_rope<<<4096, 256, 0, stream>>>(qkv, qnw, knw, freqs, qb, kb);
  vtrans<<<1024, 256, 0, stream>>>(qkv, vtb);
  attn_kernel<<<512, 256, 0, stream>>>(qb, kb, vtb, ab);
  gemm_bt<<<dim3(8, 32), 256, 0, stream>>>(ab, pb, projb, out, 4096, 1024, 1024);
}

// Round 3
// 145.155 us; speedup vs baseline: 1.4298x; 1.4298x over previous
//
#include <hip/hip_runtime.h>
#include <hip/hip_bf16.h>

#define S 4096
#define D 1024
#define NH 16
#define HD 64

typedef float f32x4 __attribute__((ext_vector_type(4)));
typedef __bf16 bf16x8 __attribute__((ext_vector_type(8)));

#define MFMA16(a, b, c) __builtin_amdgcn_mfma_f32_16x16x32_bf16((a), (b), (c), 0, 0, 0)

__device__ __forceinline__ unsigned short f2bf(float f) {
  unsigned int u = __builtin_bit_cast(unsigned int, f);
  u += 0x7FFFu + ((u >> 16) & 1u);
  return (unsigned short)(u >> 16);
}

__device__ __forceinline__ unsigned cvtpk(float lo, float hi) {
  unsigned r;
  asm("v_cvt_pk_bf16_f32 %0, %1, %2" : "=v"(r) : "v"(lo), "v"(hi));
  return r;
}

typedef __attribute__((address_space(1))) void GAS;
typedef __attribute__((address_space(3))) void LAS;

__device__ __forceinline__ void gld_lds16(const unsigned short* g, unsigned short* l) {
  __builtin_amdgcn_global_load_lds((GAS*)g, (LAS*)l, 16, 0, 0);
}

// ---------------------------------------------------------------------------
// f32 -> bf16 convert (vectorized float4 -> ushort4)
// ---------------------------------------------------------------------------
__global__ void cvt_bf16(const float* __restrict__ in, unsigned short* __restrict__ out, int n4) {
  int i = blockIdx.x * blockDim.x + threadIdx.x;
  if (i >= n4) return;
  float4 v = ((const float4*)in)[i];
  ushort4 u;
  u.x = f2bf(v.x); u.y = f2bf(v.y); u.z = f2bf(v.z); u.w = f2bf(v.w);
  ((ushort4*)out)[i] = u;
}

// ---------------------------------------------------------------------------
// C[M x N] f32 = A[M x K]bf16 @ B[N x K]^T bf16 + bias[N]
// 128x128 tile, BK=32, 256 threads (4 waves 2x2), mfma 16x16x32.
// ---------------------------------------------------------------------------
__global__ __launch_bounds__(256) void gemm_bt(const unsigned short* __restrict__ A,
                                               const unsigned short* __restrict__ B,
                                               const float* __restrict__ bias,
                                               float* __restrict__ C,
                                               int M, int N, int K) {
  __shared__ __align__(16) unsigned short As[128 * 32];
  __shared__ __align__(16) unsigned short Bs[128 * 32];
  const int t = threadIdx.x;
  const int lane = t & 63;
  const int w = t >> 6;
  const int wr = w >> 1, wc = w & 1;
  const int l15 = lane & 15, l4 = lane >> 4;
  const int m0 = blockIdx.y * 128, n0 = blockIdx.x * 128;

  f32x4 acc[4][4] = {};

  const int c0 = t, c1 = 256 + t;
  const int r0 = c0 >> 2, o0 = (c0 & 3) * 8;
  const int r1 = c1 >> 2, o1 = (c1 & 3) * 8;
  const unsigned short* Ab = A + (size_t)m0 * K;
  const unsigned short* Bb = B + (size_t)n0 * K;

  for (int k0 = 0; k0 < K; k0 += 32) {
    gld_lds16(Ab + (size_t)r0 * K + k0 + o0, &As[(w * 64) * 8]);
    gld_lds16(Ab + (size_t)r1 * K + k0 + o1, &As[(256 + w * 64) * 8]);
    gld_lds16(Bb + (size_t)r0 * K + k0 + o0, &Bs[(w * 64) * 8]);
    gld_lds16(Bb + (size_t)r1 * K + k0 + o1, &Bs[(256 + w * 64) * 8]);
    __syncthreads();
    bf16x8 af[4], bfv[4];
#pragma unroll
    for (int mf = 0; mf < 4; ++mf)
      af[mf] = *(const bf16x8*)&As[(wr * 64 + mf * 16 + l15) * 32 + l4 * 8];
#pragma unroll
    for (int nf = 0; nf < 4; ++nf)
      bfv[nf] = *(const bf16x8*)&Bs[(wc * 64 + nf * 16 + l15) * 32 + l4 * 8];
#pragma unroll
    for (int mf = 0; mf < 4; ++mf)
#pragma unroll
      for (int nf = 0; nf < 4; ++nf)
        acc[mf][nf] = MFMA16(af[mf], bfv[nf], acc[mf][nf]);
    __syncthreads();
  }

#pragma unroll
  for (int mf = 0; mf < 4; ++mf) {
#pragma unroll
    for (int nf = 0; nf < 4; ++nf) {
      int rr = m0 + wr * 64 + mf * 16 + l4 * 4;
      int cc = n0 + wc * 64 + nf * 16 + l15;
      float bv = bias[cc];
#pragma unroll
      for (int j = 0; j < 4; ++j)
        C[(size_t)(rr + j) * N + cc] = acc[mf][nf][j] + bv;
    }
  }
}

// ---------------------------------------------------------------------------
// Per-row RMSNorm (over full D=1024) + RoPE, for q and k parts of qkv.
// Writes head-major bf16: q/k [NH][S][HD].  q gets softmax scale 0.125 folded.
// ---------------------------------------------------------------------------
__global__ __launch_bounds__(256) void norm_rope(const float* __restrict__ qkv,
                                                 const float* __restrict__ qw,
                                                 const float* __restrict__ kw,
                                                 const float* __restrict__ fr,
                                                 unsigned short* __restrict__ qo,
                                                 unsigned short* __restrict__ ko) {
  __shared__ float buf[1024];
  __shared__ float red[4];
  const int s = blockIdx.x, t = threadIdx.x;
  const int lane = t & 63, w = t >> 6;
  const int e = t * 4;
  const int hh = e >> 6, dd = e & 63;
  const float* frow = fr + (size_t)s * 32;
  float cs[4], sn[4];
#pragma unroll
  for (int i = 0; i < 4; ++i) {
    float f = frow[(dd + i) & 31];
    cs[i] = cosf(f);
    sn[i] = sinf(f);
  }
  for (int part = 0; part < 2; ++part) {
    const float* row = qkv + (size_t)s * 3072 + part * 1024;
    const float* wvp = part ? kw : qw;
    unsigned short* op = part ? ko : qo;
    const float oscale = part ? 1.0f : 0.125f;  // fold softmax scale into q
    float4 v = *(const float4*)(row + e);
    float ssq = v.x * v.x + v.y * v.y + v.z * v.z + v.w * v.w;
#pragma unroll
    for (int off = 1; off < 64; off <<= 1) ssq += __shfl_xor(ssq, off, 64);
    if (part) __syncthreads();  // protect red/buf reuse across parts
    if (lane == 0) red[w] = ssq;
    __syncthreads();
    float inv = rsqrtf((red[0] + red[1] + red[2] + red[3]) * (1.0f / 1024.0f) + 1e-6f);
    float4 wv = *(const float4*)(wvp + e);
    buf[e + 0] = v.x * inv * wv.x;
    buf[e + 1] = v.y * inv * wv.y;
    buf[e + 2] = v.z * inv * wv.z;
    buf[e + 3] = v.w * inv * wv.w;
    __syncthreads();
    unsigned short ov[4];
#pragma unroll
    for (int i = 0; i < 4; ++i) {
      int di = dd + i;
      float x = buf[e + i];
      float rot = (di < 32) ? -buf[e + i + 32] : buf[e + i - 32];
      ov[i] = f2bf((x * cs[i] + rot * sn[i]) * oscale);
    }
    unsigned short* dst = op + (size_t)hh * S * HD + (size_t)s * HD + dd;
    dst[0] = ov[0]; dst[1] = ov[1]; dst[2] = ov[2]; dst[3] = ov[3];
  }
}

// ---------------------------------------------------------------------------
// V: qkv f32 [S][3072] (cols 2048..3071) -> vt bf16 [NH][HD][S] (transposed)
// ---------------------------------------------------------------------------
__global__ __launch_bounds__(256) void vtrans(const float* __restrict__ qkv,
                                              unsigned short* __restrict__ vt) {
  __shared__ unsigned short tile[64][72];
  const int bx = blockIdx.x;
  const int h = bx >> 6, st = bx & 63;
  const int s0 = st * 64;
  const int t = threadIdx.x;
#pragma unroll
  for (int i = 0; i < 16; ++i) {
    int idx = i * 256 + t;
    int sr = idx >> 6, d = idx & 63;
    tile[sr][d] = f2bf(qkv[(size_t)(s0 + sr) * 3072 + 2048 + h * 64 + d]);
  }
  __syncthreads();
#pragma unroll
  for (int i = 0; i < 16; ++i) {
    int idx = i * 256 + t;
    int d = idx >> 6, sr = idx & 63;
    vt[(size_t)h * HD * S + (size_t)d * S + s0 + sr] = tile[sr][d];
  }
}

// ---------------------------------------------------------------------------
// Flash attention within 1024-length segments. Swapped QK^T (S^T = K·Q^T),
// K/V LDS-staged (XOR-swizzled via pre-swizzled global src), double-buffered.
// grid: 1024 blocks = XCD-grouped (h,seg) x 16 q-tiles of 64 rows.
// 4 waves x 16 q-rows. q,k: [NH][S][HD] bf16 (q pre-scaled); vt: [NH][HD][S].
// ---------------------------------------------------------------------------
__global__ __launch_bounds__(256) void attn_kernel(const unsigned short* __restrict__ q,
                                                   const unsigned short* __restrict__ k,
                                                   const unsigned short* __restrict__ vt,
                                                   unsigned short* __restrict__ aout) {
  __shared__ __align__(16) unsigned short Ks[2][4096];
  __shared__ __align__(16) unsigned short Vs[2][4096];
  const int bid = blockIdx.x;
  // XCD-grouped decode: all 16 q-tiles of one (h,seg) share bid%8 -> same XCD L2
  const int xcd = bid & 7;
  const int idx = bid >> 3;
  const int gw = idx >> 4, qt = idx & 15;
  const int g = xcd * 8 + gw;
  const int h = g >> 2, seg = g & 3;
  const int t = threadIdx.x, lane = t & 63, w = t >> 6;
  const int l15 = lane & 15, l4 = lane >> 4;
  const size_t hb = (size_t)h * S * HD;
  const int q0 = seg * 1024 + qt * 64 + w * 16;
  const int kvbase = seg * 1024;

  // staging source pointers (chunk c = t for rows 0..31, c = 256+t for rows 32..63)
  const int sr = t >> 3;               // tile row 0..31
  const int scb = (t & 7) ^ (sr & 7);  // swizzled source column-chunk
  const unsigned short* ksrcA = k + hb + (size_t)(kvbase + sr) * HD + scb * 8;
  const unsigned short* ksrcB = ksrcA + 32 * HD;
  const unsigned short* vsrcA = vt + (size_t)h * HD * S + (size_t)sr * S + kvbase + scb * 8;
  const unsigned short* vsrcB = vsrcA + (size_t)32 * S;

  // Q fragment (B-operand): col=q=l15, k=hd
  const unsigned short* qp = q + hb + (size_t)(q0 + l15) * HD + l4 * 8;
  bf16x8 qf0 = *(const bf16x8*)qp;
  bf16x8 qf1 = *(const bf16x8*)(qp + 32);

  f32x4 o[4] = {};
  float m = -1e30f, l = 0.f;

  // prologue: stage tile 0
  gld_lds16(ksrcA, &Ks[0][w * 512]);
  gld_lds16(ksrcB, &Ks[0][2048 + w * 512]);
  gld_lds16(vsrcA, &Vs[0][w * 512]);
  gld_lds16(vsrcB, &Vs[0][2048 + w * 512]);
  __syncthreads();

  for (int it = 0; it < 16; ++it) {
    const int b = it & 1;
    if (it < 15) {
      const int nb = b ^ 1;
      gld_lds16(ksrcA + (it + 1) * 4096, &Ks[nb][w * 512]);
      gld_lds16(ksrcB + (it + 1) * 4096, &Ks[nb][2048 + w * 512]);
      gld_lds16(vsrcA + (it + 1) * 64, &Vs[nb][w * 512]);
      gld_lds16(vsrcB + (it + 1) * 64, &Vs[nb][2048 + w * 512]);
    }
    // ---- S^T = K . Q^T : rows kv, cols q ----
    f32x4 sacc[4] = {};
#pragma unroll
    for (int nf = 0; nf < 4; ++nf) {
      const int row = nf * 16 + l15;
      const int roff = row * 64;
      const int sw = (row & 7) << 3;
      bf16x8 k0 = *(const bf16x8*)&Ks[b][roff + ((l4 * 8) ^ sw)];
      bf16x8 k1 = *(const bf16x8*)&Ks[b][roff + ((32 + l4 * 8) ^ sw)];
      sacc[nf] = MFMA16(k0, qf0, sacc[nf]);
      sacc[nf] = MFMA16(k1, qf1, sacc[nf]);
    }
    // ---- online softmax (per lane: q = l15; 16 kv values) ----
    float tmax = -1e30f;
#pragma unroll
    for (int nf = 0; nf < 4; ++nf)
#pragma unroll
      for (int j = 0; j < 4; ++j) tmax = fmaxf(tmax, sacc[nf][j]);
    tmax = fmaxf(tmax, __shfl_xor(tmax, 16, 64));
    tmax = fmaxf(tmax, __shfl_xor(tmax, 32, 64));
    const float mn = fmaxf(m, tmax);
    const float corr = __expf(m - mn);
    m = mn;
    float rs = 0.f;
    float p[4][4];
#pragma unroll
    for (int nf = 0; nf < 4; ++nf)
#pragma unroll
      for (int j = 0; j < 4; ++j) {
        float e = __expf(sacc[nf][j] - mn);
        p[nf][j] = e;
        rs += e;
      }
    rs += __shfl_xor(rs, 16, 64);
    rs += __shfl_xor(rs, 32, 64);
    l = l * corr + rs;
#pragma unroll
    for (int nf2 = 0; nf2 < 4; ++nf2)
#pragma unroll
      for (int j = 0; j < 4; ++j) o[nf2][j] *= corr;
    // ---- pack P^T to bf16 pairs ----
    unsigned pk[4][2];
#pragma unroll
    for (int nf = 0; nf < 4; ++nf) {
      pk[nf][0] = cvtpk(p[nf][0], p[nf][1]);
      pk[nf][1] = cvtpk(p[nf][2], p[nf][3]);
    }
    // ---- O^T += V^T . P^T ----
    const int srcbase = ((lane >> 4) & 1) * 32 + l15;
    const bool hi = (lane & 32) != 0;
#pragma unroll
    for (int ks = 0; ks < 2; ++ks) {
      unsigned bw[4];
#pragma unroll
      for (int h2 = 0; h2 < 2; ++h2)
#pragma unroll
        for (int r = 0; r < 2; ++r) {
          unsigned E = (unsigned)__shfl((int)pk[2 * ks][r], srcbase + h2 * 16, 64);
          unsigned F = (unsigned)__shfl((int)pk[2 * ks + 1][r], srcbase + h2 * 16, 64);
          bw[h2 * 2 + r] = hi ? F : E;
        }
      bf16x8 pb = __builtin_bit_cast(bf16x8, *(uint4*)bw);
#pragma unroll
      for (int nf2 = 0; nf2 < 4; ++nf2) {
        const int row = nf2 * 16 + l15;
        const int roff = row * 64;
        const int sw = (row & 7) << 3;
        bf16x8 vf = *(const bf16x8*)&Vs[b][roff + ((ks * 32 + l4 * 8) ^ sw)];
        o[nf2] = MFMA16(vf, pb, o[nf2]);
      }
    }
    __syncthreads();
  }

  // epilogue: O^T frag: col=q=l15, row=d=nf2*16+l4*4+j
  const float invl = 1.0f / l;
#pragma unroll
  for (int nf2 = 0; nf2 < 4; ++nf2) {
    ushort4 u;
    u.x = f2bf(o[nf2][0] * invl);
    u.y = f2bf(o[nf2][1] * invl);
    u.z = f2bf(o[nf2][2] * invl);
    u.w = f2bf(o[nf2][3] * invl);
    *(ushort4*)(aout + (size_t)(q0 + l15) * D + h * 64 + nf2 * 16 + l4 * 4) = u;
  }
}

// ---------------------------------------------------------------------------
extern "C" void kernel_launch(void* const* d_in, const int* in_sizes, int n_in,
                              void* d_out, int out_size, void* d_ws, size_t ws_size,
                              hipStream_t stream) {
  const float* hidden = (const float*)d_in[0];
  const float* qkvw   = (const float*)d_in[1];
  const float* qkvb   = (const float*)d_in[2];
  const float* projw  = (const float*)d_in[3];
  const float* projb  = (const float*)d_in[4];
  const float* qnw    = (const float*)d_in[5];
  const float* knw    = (const float*)d_in[6];
  const float* freqs  = (const float*)d_in[7];
  float* out = (float*)d_out;
  char* ws = (char*)d_ws;

  unsigned short* hb  = (unsigned short*)(ws + 0);               // 8 MB  hidden bf16 [4096][1024]
  unsigned short* wb  = (unsigned short*)(ws + (8u << 20));      // 6 MB  qkv_w bf16 [3072][1024]
  unsigned short* pb  = (unsigned short*)(ws + (14u << 20));     // 2 MB  proj_w bf16 [1024][1024]
  float*          qkv = (float*)(ws + (16u << 20));              // 48 MB qkv f32 [4096][3072]
  unsigned short* qb  = (unsigned short*)(ws + (64u << 20));     // 8 MB  q bf16 [16][4096][64] (pre-scaled)
  unsigned short* kb  = (unsigned short*)(ws + (72u << 20));     // 8 MB  k bf16 [16][4096][64]
  unsigned short* vtb = (unsigned short*)(ws + (80u << 20));     // 8 MB  v^T bf16 [16][64][4096]
  unsigned short* ab  = (unsigned short*)(ws + (88u << 20));     // 8 MB  attn bf16 [4096][1024]

  cvt_bf16<<<4096, 256, 0, stream>>>(hidden, hb, 1048576);
  cvt_bf16<<<3072, 256, 0, stream>>>(qkvw, wb, 786432);
  cvt_bf16<<<1024, 256, 0, stream>>>(projw, pb, 262144);
  gemm_bt<<<dim3(24, 32), 256, 0, stream>>>(hb, wb, qkvb, qkv, 4096, 3072, 1024);
  norm_rope<<<4096, 256, 0, stream>>>(qkv, qnw, knw, freqs, qb, kb);
  vtrans<<<1024, 256, 0, stream>>>(qkv, vtb);
  attn_kernel<<<1024, 256, 0, stream>>>(qb, kb, vtb, ab);
  gemm_bt<<<dim3(8, 32), 256, 0, stream>>>(ab, pb, projb, out, 4096, 1024, 1024);
}